// Round 9
// baseline (437.893 us; speedup 1.0000x reference)
//
#include <hip/hip_runtime.h>
#include <math.h>

#define NN 100000
#define NE 1600000
#define ECAP 64      // ELL slots/node
#define GN 64        // nodes per gate-GEMM block
#define WSTR 296     // W^T row stride in ushorts
#define LSTR 104     // LDS bf16 row stride (96 + 8)

// binned build
#define EPB 2048     // edges per phase-A block
#define NBLKA 782    // ceil(NE/EPB)
#define BINB 256     // nodes per bin
#define NBINS 391    // ceil(NN/BINB)
#define BCAP 4736    // records per bin (mean 4092, +10 sigma)

typedef __attribute__((ext_vector_type(4))) float f32x4;
typedef __attribute__((ext_vector_type(8))) short s16x8;

__device__ __forceinline__ unsigned int bfbits(float v) {
  unsigned int b = __float_as_uint(v);
  b += 0x7fffu + ((b >> 16) & 1u);
  return b >> 16;
}
__device__ __forceinline__ float bflo(unsigned int v) { return __uint_as_float(v << 16); }
__device__ __forceinline__ float bfhi(unsigned int v) { return __uint_as_float(v & 0xffff0000u); }
__device__ __forceinline__ uint4 pack8(float4 a, float4 b) {
  return make_uint4(bfbits(a.x) | (bfbits(a.y) << 16), bfbits(a.z) | (bfbits(a.w) << 16),
                    bfbits(b.x) | (bfbits(b.y) << 16), bfbits(b.z) | (bfbits(b.w) << 16));
}
__device__ __forceinline__ uint4 scale_u4(uint4 v, float s) {
  uint4 r;
  r.x = bfbits(bflo(v.x) * s) | (bfbits(bfhi(v.x) * s) << 16);
  r.y = bfbits(bflo(v.y) * s) | (bfbits(bfhi(v.y) * s) << 16);
  r.z = bfbits(bflo(v.z) * s) | (bfbits(bfhi(v.z) * s) << 16);
  r.w = bfbits(bflo(v.w) * s) | (bfbits(bfhi(v.w) * s) << 16);
  return r;
}

// ---------------- binned graph build ----------------
// Phase A: per-block LDS bin histograms -> one reservation atomic per bin ->
// scatter records into per-bin contiguous runs (dense L2 lines).
__global__ __launch_bounds__(256) void k_binA(const int* __restrict__ src,
                                              const int* __restrict__ dst,
                                              const float* __restrict__ ew,
                                              int* __restrict__ gcur1,
                                              int* __restrict__ gcur2,
                                              int2* __restrict__ rec1,
                                              unsigned char* __restrict__ rec2) {
  __shared__ int h1[NBINS], h2[NBINS];
  int tid = threadIdx.x;
  for (int t = tid; t < NBINS; t += 256) { h1[t] = 0; h2[t] = 0; }
  __syncthreads();
  int base = blockIdx.x * EPB;
  int end = base + EPB; if (end > NE) end = NE;
  for (int e = base + tid; e < end; e += 256) {
    atomicAdd(&h1[dst[e] >> 8], 1);
    atomicAdd(&h2[src[e] >> 8], 1);
  }
  __syncthreads();
  for (int t = tid; t < NBINS; t += 256) {
    int c1 = h1[t];
    h1[t] = t * BCAP + (c1 ? atomicAdd(&gcur1[t], c1) : 0);
    int c2 = h2[t];
    h2[t] = t * BCAP + (c2 ? atomicAdd(&gcur2[t], c2) : 0);
  }
  __syncthreads();
  for (int e = base + tid; e < end; e += 256) {
    int d = dst[e], s = src[e];
    int p1 = atomicAdd(&h1[d >> 8], 1);
    rec1[p1] = make_int2(s | ((d & 255) << 20), __float_as_int(ew[e]));
    int p2 = atomicAdd(&h2[s >> 8], 1);
    rec2[p2] = (unsigned char)(s & 255);
  }
}

// Phase B: one block per dst-bin; LDS cursors; ELL writes land in the bin's
// private 128KB region. cursor[] written densely.
__global__ __launch_bounds__(256) void k_bell(const int* __restrict__ gcur1,
                                              const int2* __restrict__ rec1,
                                              int2* __restrict__ ell,
                                              int* __restrict__ cursor) {
  __shared__ int lc[BINB];
  int b = blockIdx.x, tid = threadIdx.x;
  lc[tid] = 0;
  __syncthreads();
  int cnt = gcur1[b];
  const int2* rp = rec1 + (size_t)b * BCAP;
  for (int i = tid; i < cnt; i += 256) {
    int2 r = rp[i];
    int dl = (r.x >> 20) & 255;
    int p = atomicAdd(&lc[dl], 1);
    if (p < ECAP)
      ell[(size_t)(b * 256 + dl) * ECAP + p] = make_int2(r.x & 0xFFFFF, r.y);
  }
  __syncthreads();
  int node = b * 256 + tid;
  if (node < NN) cursor[node] = lc[tid];
}

// Phase B: one block per src-bin; out-degree via LDS counters, dense write.
__global__ __launch_bounds__(256) void k_bdeg(const int* __restrict__ gcur2,
                                              const unsigned char* __restrict__ rec2,
                                              int* __restrict__ deg_out) {
  __shared__ int lc[BINB];
  int b = blockIdx.x, tid = threadIdx.x;
  lc[tid] = 0;
  __syncthreads();
  int cnt = gcur2[b];
  const unsigned char* rp = rec2 + (size_t)b * BCAP;
  for (int i = tid; i < cnt; i += 256) atomicAdd(&lc[rp[i]], 1);
  __syncthreads();
  int node = b * 256 + tid;
  if (node < NN) deg_out[node] = lc[tid];
}

// ---------------- xh0s = bf16( concat(x,h) / deg ) ----------------
__global__ __launch_bounds__(256) void k_xh0(const float* __restrict__ x,
                                             const float* __restrict__ h,
                                             const int* __restrict__ deg_out,
                                             unsigned int* __restrict__ xh0s) {
  int idx = blockIdx.x * 256 + threadIdx.x;
  if (idx >= NN * 48) return;
  int n = idx / 48, c = idx - n * 48;
  float inv = 1.f / fmaxf((float)deg_out[n], 1.f);
  float v0, v1;
  if (c < 16) {
    v0 = x[(size_t)n * 32 + 2 * c];
    v1 = x[(size_t)n * 32 + 2 * c + 1];
  } else {
    v0 = h[(size_t)n * 64 + 2 * (c - 16)];
    v1 = h[(size_t)n * 64 + 2 * (c - 16) + 1];
  }
  xh0s[idx] = bfbits(v0 * inv) | (bfbits(v1 * inv) << 16);
}

// ---------------- W prep ----------------
__global__ __launch_bounds__(256) void k_wprep(const float* __restrict__ Wr,
                                               const float* __restrict__ Wz,
                                               const float* __restrict__ Wc,
                                               unsigned short* __restrict__ wt_rz,
                                               unsigned short* __restrict__ wt_c) {
  int idx = blockIdx.x * 256 + threadIdx.x;
  if (idx >= 192 * 36) return;
  int col = idx % 192;
  int k0 = (idx / 192) * 8;
  unsigned int packed[4];
#pragma unroll
  for (int p = 0; p < 4; ++p) {
    unsigned int lo, hi;
#pragma unroll
    for (int e = 0; e < 2; ++e) {
      int k = k0 + p * 2 + e;
      int t = k / 96, kl = k - t * 96;
      float v;
      if (col < 64) v = Wr[t * 6144 + kl * 64 + col];
      else if (col < 128) v = Wz[t * 6144 + kl * 64 + (col - 64)];
      else v = Wc[t * 6144 + kl * 64 + (col - 128)];
      if (e == 0) lo = bfbits(v); else hi = bfbits(v);
    }
    packed[p] = lo | (hi << 16);
  }
  unsigned short* dstp = (col < 128) ? (wt_rz + col * WSTR + k0)
                                     : (wt_c + (col - 128) * WSTR + k0);
  *reinterpret_cast<uint4*>(dstp) =
      make_uint4(packed[0], packed[1], packed[2], packed[3]);
}

// ---------------- propagation: half-wave per node, ELL, 4x unrolled ----------
__global__ __launch_bounds__(256) void k_prop96e(const uint2* __restrict__ in,
                                                 uint2* __restrict__ out,
                                                 const int* __restrict__ cnt_arr,
                                                 const int* __restrict__ deg_out,
                                                 const int2* __restrict__ ell) {
  int hw = (blockIdx.x * 256 + threadIdx.x) >> 5;
  int lane = threadIdx.x & 31;
  if (hw >= NN) return;
  int cnt = cnt_arr[hw];
  if (cnt > ECAP) cnt = ECAP;
  const int2* ep = ell + (size_t)hw * ECAP;
  bool act = lane < 24;
  float a0 = 0.f, a1 = 0.f, a2 = 0.f, a3 = 0.f;
  float b0 = 0.f, b1 = 0.f, b2 = 0.f, b3 = 0.f;
  int i = 0;
  for (; i + 4 <= cnt; i += 4) {
    int2 e0 = ep[i], e1 = ep[i + 1], e2 = ep[i + 2], e3 = ep[i + 3];
    if (act) {
      uint2 v0 = in[(size_t)e0.x * 24 + lane];
      uint2 v1 = in[(size_t)e1.x * 24 + lane];
      uint2 v2 = in[(size_t)e2.x * 24 + lane];
      uint2 v3 = in[(size_t)e3.x * 24 + lane];
      float w0 = __int_as_float(e0.y), w1 = __int_as_float(e1.y);
      float w2 = __int_as_float(e2.y), w3 = __int_as_float(e3.y);
      a0 = fmaf(w0, bflo(v0.x), a0); a1 = fmaf(w0, bfhi(v0.x), a1);
      a2 = fmaf(w0, bflo(v0.y), a2); a3 = fmaf(w0, bfhi(v0.y), a3);
      b0 = fmaf(w1, bflo(v1.x), b0); b1 = fmaf(w1, bfhi(v1.x), b1);
      b2 = fmaf(w1, bflo(v1.y), b2); b3 = fmaf(w1, bfhi(v1.y), b3);
      a0 = fmaf(w2, bflo(v2.x), a0); a1 = fmaf(w2, bfhi(v2.x), a1);
      a2 = fmaf(w2, bflo(v2.y), a2); a3 = fmaf(w2, bfhi(v2.y), a3);
      b0 = fmaf(w3, bflo(v3.x), b0); b1 = fmaf(w3, bfhi(v3.x), b1);
      b2 = fmaf(w3, bflo(v3.y), b2); b3 = fmaf(w3, bfhi(v3.y), b3);
    }
  }
  for (; i < cnt; ++i) {
    int2 e = ep[i];
    if (act) {
      uint2 v = in[(size_t)e.x * 24 + lane];
      float w = __int_as_float(e.y);
      a0 = fmaf(w, bflo(v.x), a0); a1 = fmaf(w, bfhi(v.x), a1);
      a2 = fmaf(w, bflo(v.y), a2); a3 = fmaf(w, bfhi(v.y), a3);
    }
  }
  if (act) {
    float inv = 1.f / fmaxf((float)deg_out[hw], 1.f);
    uint2 o;
    o.x = bfbits((a0 + b0) * inv) | (bfbits((a1 + b1) * inv) << 16);
    o.y = bfbits((a2 + b2) * inv) | (bfbits((a3 + b3) * inv) << 16);
    out[(size_t)hw * 24 + lane] = o;
  }
}

__global__ __launch_bounds__(256) void k_prop64e(const unsigned int* __restrict__ in,
                                                 unsigned int* __restrict__ out,
                                                 const int* __restrict__ cnt_arr,
                                                 const int* __restrict__ deg_out,
                                                 const int2* __restrict__ ell) {
  int hw = (blockIdx.x * 256 + threadIdx.x) >> 5;
  int lane = threadIdx.x & 31;
  if (hw >= NN) return;
  int cnt = cnt_arr[hw];
  if (cnt > ECAP) cnt = ECAP;
  const int2* ep = ell + (size_t)hw * ECAP;
  float a0 = 0.f, a1 = 0.f, b0 = 0.f, b1 = 0.f;
  int i = 0;
  for (; i + 4 <= cnt; i += 4) {
    int2 e0 = ep[i], e1 = ep[i + 1], e2 = ep[i + 2], e3 = ep[i + 3];
    unsigned int v0 = in[(size_t)e0.x * 32 + lane];
    unsigned int v1 = in[(size_t)e1.x * 32 + lane];
    unsigned int v2 = in[(size_t)e2.x * 32 + lane];
    unsigned int v3 = in[(size_t)e3.x * 32 + lane];
    float w0 = __int_as_float(e0.y), w1 = __int_as_float(e1.y);
    float w2 = __int_as_float(e2.y), w3 = __int_as_float(e3.y);
    a0 = fmaf(w0, bflo(v0), a0); a1 = fmaf(w0, bfhi(v0), a1);
    b0 = fmaf(w1, bflo(v1), b0); b1 = fmaf(w1, bfhi(v1), b1);
    a0 = fmaf(w2, bflo(v2), a0); a1 = fmaf(w2, bfhi(v2), a1);
    b0 = fmaf(w3, bflo(v3), b0); b1 = fmaf(w3, bfhi(v3), b1);
  }
  for (; i < cnt; ++i) {
    int2 e = ep[i];
    unsigned int v = in[(size_t)e.x * 32 + lane];
    float w = __int_as_float(e.y);
    a0 = fmaf(w, bflo(v), a0); a1 = fmaf(w, bfhi(v), a1);
  }
  float inv = 1.f / fmaxf((float)deg_out[hw], 1.f);
  out[(size_t)hw * 32 + lane] = bfbits((a0 + b0) * inv) | (bfbits((a1 + b1) * inv) << 16);
}

// ---------------- gate staging helpers ----------------
__device__ __forceinline__ void stage_f32f32(unsigned short* sA, int nb0,
                                             const float* __restrict__ srcA,
                                             const float* __restrict__ srcB) {
  for (int i = threadIdx.x; i < GN * 12; i += 256) {
    int n = i / 12, ch = i % 12;
    int g = nb0 + n;
    uint4 v = make_uint4(0, 0, 0, 0);
    if (g < NN) {
      if (ch < 4) {
        float4 f0 = *reinterpret_cast<const float4*>(srcA + (size_t)g * 32 + ch * 8);
        float4 f1 = *reinterpret_cast<const float4*>(srcA + (size_t)g * 32 + ch * 8 + 4);
        v = pack8(f0, f1);
      } else {
        float4 f0 = *reinterpret_cast<const float4*>(srcB + (size_t)g * 64 + (ch - 4) * 8);
        float4 f1 = *reinterpret_cast<const float4*>(srcB + (size_t)g * 64 + (ch - 4) * 8 + 4);
        v = pack8(f0, f1);
      }
    }
    *reinterpret_cast<uint4*>(&sA[n * LSTR + ch * 8]) = v;
  }
}

__device__ __forceinline__ void stage_s96(unsigned short* sA, int nb0,
                                          const unsigned short* __restrict__ src,
                                          const int* __restrict__ deg) {
  for (int i = threadIdx.x; i < GN * 12; i += 256) {
    int n = i / 12, ch = i % 12;
    int g = nb0 + n;
    uint4 v = make_uint4(0, 0, 0, 0);
    if (g < NN) {
      float dg = fmaxf((float)deg[g], 1.f);
      v = scale_u4(*reinterpret_cast<const uint4*>(src + (size_t)g * 96 + ch * 8), dg);
    }
    *reinterpret_cast<uint4*>(&sA[n * LSTR + ch * 8]) = v;
  }
}

__device__ __forceinline__ void stage_f32_s64(unsigned short* sA, int nb0,
                                              const float* __restrict__ srcA,
                                              const unsigned short* __restrict__ srcB,
                                              const int* __restrict__ deg) {
  for (int i = threadIdx.x; i < GN * 12; i += 256) {
    int n = i / 12, ch = i % 12;
    int g = nb0 + n;
    uint4 v = make_uint4(0, 0, 0, 0);
    if (g < NN) {
      if (ch < 4) {
        float4 f0 = *reinterpret_cast<const float4*>(srcA + (size_t)g * 32 + ch * 8);
        float4 f1 = *reinterpret_cast<const float4*>(srcA + (size_t)g * 32 + ch * 8 + 4);
        v = pack8(f0, f1);
      } else {
        float dg = fmaxf((float)deg[g], 1.f);
        v = scale_u4(*reinterpret_cast<const uint4*>(srcB + (size_t)g * 64 + (ch - 4) * 8), dg);
      }
    }
    *reinterpret_cast<uint4*>(&sA[n * LSTR + ch * 8]) = v;
  }
}

__device__ __forceinline__ void stage_s96_s64(unsigned short* sA, int nb0,
                                              const unsigned short* __restrict__ srcA,
                                              const unsigned short* __restrict__ srcB,
                                              const int* __restrict__ deg) {
  for (int i = threadIdx.x; i < GN * 12; i += 256) {
    int n = i / 12, ch = i % 12;
    int g = nb0 + n;
    uint4 v = make_uint4(0, 0, 0, 0);
    if (g < NN) {
      float dg = fmaxf((float)deg[g], 1.f);
      if (ch < 4) v = scale_u4(*reinterpret_cast<const uint4*>(srcA + (size_t)g * 96 + ch * 8), dg);
      else v = scale_u4(*reinterpret_cast<const uint4*>(srcB + (size_t)g * 64 + (ch - 4) * 8), dg);
    }
    *reinterpret_cast<uint4*>(&sA[n * LSTR + ch * 8]) = v;
  }
}

template <int NCOLS>
__device__ __forceinline__ void stage_w(unsigned short* sW,
                                        const unsigned short* __restrict__ wt, int t) {
  for (int i = threadIdx.x; i < NCOLS * 12; i += 256) {
    int col = i / 12, ch = i % 12;
    uint4 v = *reinterpret_cast<const uint4*>(wt + col * WSTR + t * 96 + ch * 8);
    *reinterpret_cast<uint4*>(&sW[col * LSTR + ch * 8]) = v;
  }
}

// ---------------- gates: bf16 MFMA GEMM ----------------
__global__ __launch_bounds__(256) void k_rz(const float* __restrict__ x,
                                            const float* __restrict__ h,
                                            const unsigned short* __restrict__ xh1s,
                                            const unsigned short* __restrict__ xh2s,
                                            const unsigned short* __restrict__ wt_rz,
                                            const float* __restrict__ br,
                                            const float* __restrict__ bz,
                                            const int* __restrict__ deg,
                                            unsigned short* __restrict__ rhs,
                                            float* __restrict__ zb) {
  __shared__ alignas(16) unsigned short sA[GN * LSTR];
  __shared__ alignas(16) unsigned short sW[128 * LSTR];
  int tid = threadIdx.x;
  int nb0 = blockIdx.x * GN;
  int wv = tid >> 6, l = tid & 63;
  int l15 = l & 15, lg = l >> 4;
  int n0 = wv * 32;

  f32x4 acc[4][2];
#pragma unroll
  for (int nt = 0; nt < 2; ++nt) {
    int colc = n0 + nt * 16 + l15;
    float bias = (colc < 64) ? br[colc] : bz[colc - 64];
#pragma unroll
    for (int mt = 0; mt < 4; ++mt) acc[mt][nt] = {bias, bias, bias, bias};
  }

#pragma unroll
  for (int t = 0; t < 3; ++t) {
    if (t == 0) stage_f32f32(sA, nb0, x, h);
    else if (t == 1) stage_s96(sA, nb0, xh1s, deg);
    else stage_s96(sA, nb0, xh2s, deg);
    stage_w<128>(sW, wt_rz, t);
    __syncthreads();
#pragma unroll
    for (int ks = 0; ks < 3; ++ks) {
      int kb = ks * 32 + lg * 8;
      s16x8 af[4];
#pragma unroll
      for (int mt = 0; mt < 4; ++mt)
        af[mt] = *reinterpret_cast<const s16x8*>(&sA[(mt * 16 + l15) * LSTR + kb]);
      s16x8 bf0 = *reinterpret_cast<const s16x8*>(&sW[(n0 + l15) * LSTR + kb]);
      s16x8 bf1 = *reinterpret_cast<const s16x8*>(&sW[(n0 + 16 + l15) * LSTR + kb]);
#pragma unroll
      for (int mt = 0; mt < 4; ++mt) {
        acc[mt][0] = __builtin_amdgcn_mfma_f32_16x16x32_bf16(af[mt], bf0, acc[mt][0], 0, 0, 0);
        acc[mt][1] = __builtin_amdgcn_mfma_f32_16x16x32_bf16(af[mt], bf1, acc[mt][1], 0, 0, 0);
      }
    }
    __syncthreads();
  }

#pragma unroll
  for (int mt = 0; mt < 4; ++mt) {
#pragma unroll
    for (int nt = 0; nt < 2; ++nt) {
      int colc = n0 + nt * 16 + l15;
#pragma unroll
      for (int r = 0; r < 4; ++r) {
        int g = nb0 + mt * 16 + lg * 4 + r;
        if (g < NN) {
          float pre = acc[mt][nt][r];
          float sg = 1.f / (1.f + expf(-pre));
          if (colc < 64) {
            float hv = h[(size_t)g * 64 + colc];
            float inv = 1.f / fmaxf((float)deg[g], 1.f);
            rhs[(size_t)g * 64 + colc] = (unsigned short)bfbits(sg * hv * inv);
          } else {
            zb[(size_t)g * 64 + (colc - 64)] = sg;
          }
        }
      }
    }
  }
}

__global__ __launch_bounds__(256) void k_c(const float* __restrict__ x,
                                           const float* __restrict__ h,
                                           const unsigned short* __restrict__ rhs,
                                           const unsigned short* __restrict__ xh1s,
                                           const unsigned short* __restrict__ xh2s,
                                           const unsigned short* __restrict__ rh1s,
                                           const unsigned short* __restrict__ rh2s,
                                           const unsigned short* __restrict__ wt_c,
                                           const float* __restrict__ bc,
                                           const float* __restrict__ zb,
                                           const int* __restrict__ deg,
                                           float* __restrict__ out) {
  __shared__ alignas(16) unsigned short sA[GN * LSTR];
  __shared__ alignas(16) unsigned short sW[64 * LSTR];
  int tid = threadIdx.x;
  int nb0 = blockIdx.x * GN;
  int wv = tid >> 6, l = tid & 63;
  int l15 = l & 15, lg = l >> 4;
  int n0 = wv * 16;

  float bias = bc[n0 + l15];
  f32x4 acc[4];
#pragma unroll
  for (int mt = 0; mt < 4; ++mt) acc[mt] = {bias, bias, bias, bias};

#pragma unroll
  for (int t = 0; t < 3; ++t) {
    if (t == 0) stage_f32_s64(sA, nb0, x, rhs, deg);
    else if (t == 1) stage_s96_s64(sA, nb0, xh1s, rh1s, deg);
    else stage_s96_s64(sA, nb0, xh2s, rh2s, deg);
    stage_w<64>(sW, wt_c, t);
    __syncthreads();
#pragma unroll
    for (int ks = 0; ks < 3; ++ks) {
      int kb = ks * 32 + lg * 8;
      s16x8 bf0 = *reinterpret_cast<const s16x8*>(&sW[(n0 + l15) * LSTR + kb]);
#pragma unroll
      for (int mt = 0; mt < 4; ++mt) {
        s16x8 af = *reinterpret_cast<const s16x8*>(&sA[(mt * 16 + l15) * LSTR + kb]);
        acc[mt] = __builtin_amdgcn_mfma_f32_16x16x32_bf16(af, bf0, acc[mt], 0, 0, 0);
      }
    }
    __syncthreads();
  }

  int colc = n0 + l15;
#pragma unroll
  for (int mt = 0; mt < 4; ++mt) {
#pragma unroll
    for (int r = 0; r < 4; ++r) {
      int g = nb0 + mt * 16 + lg * 4 + r;
      if (g < NN) {
        float cv = tanhf(acc[mt][r]);
        float z = zb[(size_t)g * 64 + colc];
        float hv = h[(size_t)g * 64 + colc];
        out[(size_t)g * 64 + colc] = z * hv + (1.f - z) * cv;
      }
    }
  }
}

// ---------------- launch ----------------
extern "C" void kernel_launch(void* const* d_in, const int* in_sizes, int n_in,
                              void* d_out, int out_size, void* d_ws, size_t ws_size,
                              hipStream_t stream) {
  const float* x = (const float*)d_in[0];
  const float* h = (const float*)d_in[1];
  const int* eidx = (const int*)d_in[2];
  const float* ew = (const float*)d_in[3];
  const float* Wr = (const float*)d_in[4];
  const float* br = (const float*)d_in[5];
  const float* Wz = (const float*)d_in[6];
  const float* bz = (const float*)d_in[7];
  const float* Wc = (const float*)d_in[8];
  const float* bc = (const float*)d_in[9];
  const int* src = eidx;
  const int* dst = eidx + NE;
  float* out = (float*)d_out;

  int* ip = (int*)d_ws;
  int* gcur1 = ip;                          // 512
  int* gcur2 = ip + 512;                    // 512
  int* deg_out = ip + 1024;                 // NN
  int* cursor = deg_out + NN;               // NN
  int2* rec1 = (int2*)(cursor + NN);        // NBINS*BCAP int2
  unsigned char* rec2 = (unsigned char*)(rec1 + (size_t)NBINS * BCAP);  // NBINS*BCAP
  int2* ell = (int2*)(rec2 + ((size_t)NBINS * BCAP + 8) / 8 * 8);       // NN*ECAP
  float* zb = (float*)(ell + (size_t)NN * ECAP);                        // NN*64 f32
  unsigned short* xh0s = (unsigned short*)(zb + (size_t)NN * 64);       // NN*96 bf16
  unsigned short* xh1s = xh0s + (size_t)NN * 96;
  unsigned short* xh2s = xh1s + (size_t)NN * 96;
  unsigned short* rhs  = xh2s + (size_t)NN * 96;   // NN*64 bf16
  unsigned short* rh1s = rhs + (size_t)NN * 64;
  unsigned short* rh2s = rh1s + (size_t)NN * 64;
  unsigned short* wt_rz = rh2s + (size_t)NN * 64;  // 128*WSTR
  unsigned short* wt_c = wt_rz + 128 * WSTR;       // 64*WSTR

  hipMemsetAsync(ip, 0, 1024 * sizeof(int), stream);

  dim3 blk(256);
  k_wprep<<<dim3((192 * 36 + 255) / 256), blk, 0, stream>>>(Wr, Wz, Wc, wt_rz, wt_c);
  k_binA<<<dim3(NBLKA), blk, 0, stream>>>(src, dst, ew, gcur1, gcur2, rec1, rec2);
  k_bell<<<dim3(NBINS), blk, 0, stream>>>(gcur1, rec1, ell, cursor);
  k_bdeg<<<dim3(NBINS), blk, 0, stream>>>(gcur2, rec2, deg_out);
  k_xh0<<<dim3(NN * 48 / 256), blk, 0, stream>>>(x, h, deg_out, (unsigned int*)xh0s);

  k_prop96e<<<dim3(NN / 8), blk, 0, stream>>>((const uint2*)xh0s, (uint2*)xh1s,
                                              cursor, deg_out, ell);
  k_prop96e<<<dim3(NN / 8), blk, 0, stream>>>((const uint2*)xh1s, (uint2*)xh2s,
                                              cursor, deg_out, ell);
  k_rz<<<dim3((NN + GN - 1) / GN), blk, 0, stream>>>(x, h, xh1s, xh2s, wt_rz, br, bz,
                                                     deg_out, rhs, zb);
  k_prop64e<<<dim3(NN / 8), blk, 0, stream>>>((const unsigned int*)rhs,
                                              (unsigned int*)rh1s, cursor, deg_out, ell);
  k_prop64e<<<dim3(NN / 8), blk, 0, stream>>>((const unsigned int*)rh1s,
                                              (unsigned int*)rh2s, cursor, deg_out, ell);
  k_c<<<dim3((NN + GN - 1) / GN), blk, 0, stream>>>(x, h, rhs, xh1s, xh2s, rh1s, rh2s,
                                                    wt_c, bc, zb, deg_out, out);
}

// Round 10
// 426.729 us; speedup vs baseline: 1.0262x; 1.0262x over previous
//
#include <hip/hip_runtime.h>
#include <math.h>

#define NN 100000
#define NE 1600000
#define ECAP 64      // ELL slots/node
#define GN 64        // nodes per gate-GEMM block
#define WSTR 296     // W^T row stride in ushorts
#define LSTR 104     // LDS bf16 row stride (96 + 8)

// binned build
#define EPB 4096     // edges per phase-A block
#define NBLKA 391    // ceil(NE/EPB)
#define BINB 256     // nodes per bin
#define NBINS 391    // ceil(NN/BINB)
#define BCAP 4736    // records per bin (mean 4092, +10 sigma)

typedef __attribute__((ext_vector_type(4))) float f32x4;
typedef __attribute__((ext_vector_type(8))) short s16x8;

__device__ __forceinline__ unsigned int bfbits(float v) {
  unsigned int b = __float_as_uint(v);
  b += 0x7fffu + ((b >> 16) & 1u);
  return b >> 16;
}
__device__ __forceinline__ float bflo(unsigned int v) { return __uint_as_float(v << 16); }
__device__ __forceinline__ float bfhi(unsigned int v) { return __uint_as_float(v & 0xffff0000u); }
__device__ __forceinline__ uint4 pack8(float4 a, float4 b) {
  return make_uint4(bfbits(a.x) | (bfbits(a.y) << 16), bfbits(a.z) | (bfbits(a.w) << 16),
                    bfbits(b.x) | (bfbits(b.y) << 16), bfbits(b.z) | (bfbits(b.w) << 16));
}

// ---------------- binned graph build ----------------
__global__ __launch_bounds__(256) void k_binA(const int* __restrict__ src,
                                              const int* __restrict__ dst,
                                              const float* __restrict__ ew,
                                              int* __restrict__ gcur1,
                                              int* __restrict__ gcur2,
                                              int2* __restrict__ rec1,
                                              unsigned char* __restrict__ rec2) {
  __shared__ int h1[NBINS], h2[NBINS];
  int tid = threadIdx.x;
  for (int t = tid; t < NBINS; t += 256) { h1[t] = 0; h2[t] = 0; }
  __syncthreads();
  int base = blockIdx.x * EPB;
  int end = base + EPB; if (end > NE) end = NE;
  for (int e = base + tid; e < end; e += 256) {
    atomicAdd(&h1[dst[e] >> 8], 1);
    atomicAdd(&h2[src[e] >> 8], 1);
  }
  __syncthreads();
  for (int t = tid; t < NBINS; t += 256) {
    int c1 = h1[t];
    h1[t] = t * BCAP + (c1 ? atomicAdd(&gcur1[t], c1) : 0);
    int c2 = h2[t];
    h2[t] = t * BCAP + (c2 ? atomicAdd(&gcur2[t], c2) : 0);
  }
  __syncthreads();
  for (int e = base + tid; e < end; e += 256) {
    int d = dst[e], s = src[e];
    int p1 = atomicAdd(&h1[d >> 8], 1);
    rec1[p1] = make_int2(s | ((d & 255) << 20), __float_as_int(ew[e]));
    int p2 = atomicAdd(&h2[s >> 8], 1);
    rec2[p2] = (unsigned char)(s & 255);
  }
}

// out-degree first (one block per src-bin, LDS counters, dense write)
__global__ __launch_bounds__(256) void k_bdeg(const int* __restrict__ gcur2,
                                              const unsigned char* __restrict__ rec2,
                                              int* __restrict__ deg_out) {
  __shared__ int lc[BINB];
  int b = blockIdx.x, tid = threadIdx.x;
  lc[tid] = 0;
  __syncthreads();
  int cnt = gcur2[b];
  const unsigned char* rp = rec2 + (size_t)b * BCAP;
  for (int i = tid; i < cnt; i += 256) atomicAdd(&lc[rp[i]], 1);
  __syncthreads();
  int node = b * 256 + tid;
  if (node < NN) deg_out[node] = lc[tid];
}

// then ELL fill with normalization applied here (deg_out ready):
// w = ew / max(deg_out[src],1). One L2 gather of deg per record.
__global__ __launch_bounds__(256) void k_bell(const int* __restrict__ gcur1,
                                              const int2* __restrict__ rec1,
                                              const int* __restrict__ deg_out,
                                              int2* __restrict__ ell,
                                              int* __restrict__ cursor) {
  __shared__ int lc[BINB];
  int b = blockIdx.x, tid = threadIdx.x;
  lc[tid] = 0;
  __syncthreads();
  int cnt = gcur1[b];
  const int2* rp = rec1 + (size_t)b * BCAP;
  for (int i = tid; i < cnt; i += 256) {
    int2 r = rp[i];
    int s = r.x & 0xFFFFF;
    int dl = (r.x >> 20) & 255;
    float w = __int_as_float(r.y) / fmaxf((float)deg_out[s], 1.0f);
    int p = atomicAdd(&lc[dl], 1);
    if (p < ECAP)
      ell[(size_t)(b * 256 + dl) * ECAP + p] = make_int2(s, __float_as_int(w));
  }
  __syncthreads();
  int node = b * 256 + tid;
  if (node < NN) cursor[node] = lc[tid];
}

// ---------------- xh0 = bf16 concat(x,h) (unscaled) ----------------
__global__ __launch_bounds__(256) void k_xh0(const float* __restrict__ x,
                                             const float* __restrict__ h,
                                             unsigned int* __restrict__ xh0) {
  int idx = blockIdx.x * 256 + threadIdx.x;
  if (idx >= NN * 48) return;
  int n = idx / 48, c = idx - n * 48;
  float v0, v1;
  if (c < 16) {
    v0 = x[(size_t)n * 32 + 2 * c];
    v1 = x[(size_t)n * 32 + 2 * c + 1];
  } else {
    v0 = h[(size_t)n * 64 + 2 * (c - 16)];
    v1 = h[(size_t)n * 64 + 2 * (c - 16) + 1];
  }
  xh0[idx] = bfbits(v0) | (bfbits(v1) << 16);
}

// ---------------- W prep ----------------
__global__ __launch_bounds__(256) void k_wprep(const float* __restrict__ Wr,
                                               const float* __restrict__ Wz,
                                               const float* __restrict__ Wc,
                                               unsigned short* __restrict__ wt_rz,
                                               unsigned short* __restrict__ wt_c) {
  int idx = blockIdx.x * 256 + threadIdx.x;
  if (idx >= 192 * 36) return;
  int col = idx % 192;
  int k0 = (idx / 192) * 8;
  unsigned int packed[4];
#pragma unroll
  for (int p = 0; p < 4; ++p) {
    unsigned int lo, hi;
#pragma unroll
    for (int e = 0; e < 2; ++e) {
      int k = k0 + p * 2 + e;
      int t = k / 96, kl = k - t * 96;
      float v;
      if (col < 64) v = Wr[t * 6144 + kl * 64 + col];
      else if (col < 128) v = Wz[t * 6144 + kl * 64 + (col - 64)];
      else v = Wc[t * 6144 + kl * 64 + (col - 128)];
      if (e == 0) lo = bfbits(v); else hi = bfbits(v);
    }
    packed[p] = lo | (hi << 16);
  }
  unsigned short* dstp = (col < 128) ? (wt_rz + col * WSTR + k0)
                                     : (wt_c + (col - 128) * WSTR + k0);
  *reinterpret_cast<uint4*>(dstp) =
      make_uint4(packed[0], packed[1], packed[2], packed[3]);
}

// ---------------- propagation: half-wave per node, ELL, 4x unrolled ----------
__global__ __launch_bounds__(256) void k_prop96e(const uint2* __restrict__ in,
                                                 uint2* __restrict__ out,
                                                 const int* __restrict__ cnt_arr,
                                                 const int2* __restrict__ ell) {
  int hw = (blockIdx.x * 256 + threadIdx.x) >> 5;
  int lane = threadIdx.x & 31;
  if (hw >= NN) return;
  int cnt = cnt_arr[hw];
  if (cnt > ECAP) cnt = ECAP;
  const int2* ep = ell + (size_t)hw * ECAP;
  bool act = lane < 24;
  float a0 = 0.f, a1 = 0.f, a2 = 0.f, a3 = 0.f;
  float b0 = 0.f, b1 = 0.f, b2 = 0.f, b3 = 0.f;
  int i = 0;
  for (; i + 4 <= cnt; i += 4) {
    int2 e0 = ep[i], e1 = ep[i + 1], e2 = ep[i + 2], e3 = ep[i + 3];
    if (act) {
      uint2 v0 = in[(size_t)e0.x * 24 + lane];
      uint2 v1 = in[(size_t)e1.x * 24 + lane];
      uint2 v2 = in[(size_t)e2.x * 24 + lane];
      uint2 v3 = in[(size_t)e3.x * 24 + lane];
      float w0 = __int_as_float(e0.y), w1 = __int_as_float(e1.y);
      float w2 = __int_as_float(e2.y), w3 = __int_as_float(e3.y);
      a0 = fmaf(w0, bflo(v0.x), a0); a1 = fmaf(w0, bfhi(v0.x), a1);
      a2 = fmaf(w0, bflo(v0.y), a2); a3 = fmaf(w0, bfhi(v0.y), a3);
      b0 = fmaf(w1, bflo(v1.x), b0); b1 = fmaf(w1, bfhi(v1.x), b1);
      b2 = fmaf(w1, bflo(v1.y), b2); b3 = fmaf(w1, bfhi(v1.y), b3);
      a0 = fmaf(w2, bflo(v2.x), a0); a1 = fmaf(w2, bfhi(v2.x), a1);
      a2 = fmaf(w2, bflo(v2.y), a2); a3 = fmaf(w2, bfhi(v2.y), a3);
      b0 = fmaf(w3, bflo(v3.x), b0); b1 = fmaf(w3, bfhi(v3.x), b1);
      b2 = fmaf(w3, bflo(v3.y), b2); b3 = fmaf(w3, bfhi(v3.y), b3);
    }
  }
  for (; i < cnt; ++i) {
    int2 e = ep[i];
    if (act) {
      uint2 v = in[(size_t)e.x * 24 + lane];
      float w = __int_as_float(e.y);
      a0 = fmaf(w, bflo(v.x), a0); a1 = fmaf(w, bfhi(v.x), a1);
      a2 = fmaf(w, bflo(v.y), a2); a3 = fmaf(w, bfhi(v.y), a3);
    }
  }
  if (act) {
    uint2 o;
    o.x = bfbits(a0 + b0) | (bfbits(a1 + b1) << 16);
    o.y = bfbits(a2 + b2) | (bfbits(a3 + b3) << 16);
    out[(size_t)hw * 24 + lane] = o;
  }
}

__global__ __launch_bounds__(256) void k_prop64e(const unsigned int* __restrict__ in,
                                                 unsigned int* __restrict__ out,
                                                 const int* __restrict__ cnt_arr,
                                                 const int2* __restrict__ ell) {
  int hw = (blockIdx.x * 256 + threadIdx.x) >> 5;
  int lane = threadIdx.x & 31;
  if (hw >= NN) return;
  int cnt = cnt_arr[hw];
  if (cnt > ECAP) cnt = ECAP;
  const int2* ep = ell + (size_t)hw * ECAP;
  float a0 = 0.f, a1 = 0.f, b0 = 0.f, b1 = 0.f;
  int i = 0;
  for (; i + 4 <= cnt; i += 4) {
    int2 e0 = ep[i], e1 = ep[i + 1], e2 = ep[i + 2], e3 = ep[i + 3];
    unsigned int v0 = in[(size_t)e0.x * 32 + lane];
    unsigned int v1 = in[(size_t)e1.x * 32 + lane];
    unsigned int v2 = in[(size_t)e2.x * 32 + lane];
    unsigned int v3 = in[(size_t)e3.x * 32 + lane];
    float w0 = __int_as_float(e0.y), w1 = __int_as_float(e1.y);
    float w2 = __int_as_float(e2.y), w3 = __int_as_float(e3.y);
    a0 = fmaf(w0, bflo(v0), a0); a1 = fmaf(w0, bfhi(v0), a1);
    b0 = fmaf(w1, bflo(v1), b0); b1 = fmaf(w1, bfhi(v1), b1);
    a0 = fmaf(w2, bflo(v2), a0); a1 = fmaf(w2, bfhi(v2), a1);
    b0 = fmaf(w3, bflo(v3), b0); b1 = fmaf(w3, bfhi(v3), b1);
  }
  for (; i < cnt; ++i) {
    int2 e = ep[i];
    unsigned int v = in[(size_t)e.x * 32 + lane];
    float w = __int_as_float(e.y);
    a0 = fmaf(w, bflo(v), a0); a1 = fmaf(w, bfhi(v), a1);
  }
  out[(size_t)hw * 32 + lane] = bfbits(a0 + b0) | (bfbits(a1 + b1) << 16);
}

// ---------------- gate staging helpers (plain copies) ----------------
__device__ __forceinline__ void stage_f32f32(unsigned short* sA, int nb0,
                                             const float* __restrict__ srcA,
                                             const float* __restrict__ srcB) {
  for (int i = threadIdx.x; i < GN * 12; i += 256) {
    int n = i / 12, ch = i % 12;
    int g = nb0 + n;
    uint4 v = make_uint4(0, 0, 0, 0);
    if (g < NN) {
      if (ch < 4) {
        float4 f0 = *reinterpret_cast<const float4*>(srcA + (size_t)g * 32 + ch * 8);
        float4 f1 = *reinterpret_cast<const float4*>(srcA + (size_t)g * 32 + ch * 8 + 4);
        v = pack8(f0, f1);
      } else {
        float4 f0 = *reinterpret_cast<const float4*>(srcB + (size_t)g * 64 + (ch - 4) * 8);
        float4 f1 = *reinterpret_cast<const float4*>(srcB + (size_t)g * 64 + (ch - 4) * 8 + 4);
        v = pack8(f0, f1);
      }
    }
    *reinterpret_cast<uint4*>(&sA[n * LSTR + ch * 8]) = v;
  }
}

__device__ __forceinline__ void stage_copy96(unsigned short* sA, int nb0,
                                             const unsigned short* __restrict__ src) {
  for (int i = threadIdx.x; i < GN * 12; i += 256) {
    int n = i / 12, ch = i % 12;
    int g = nb0 + n;
    uint4 v = make_uint4(0, 0, 0, 0);
    if (g < NN) v = *reinterpret_cast<const uint4*>(src + (size_t)g * 96 + ch * 8);
    *reinterpret_cast<uint4*>(&sA[n * LSTR + ch * 8]) = v;
  }
}

__device__ __forceinline__ void stage_f32bf(unsigned short* sA, int nb0,
                                            const float* __restrict__ srcA,
                                            const unsigned short* __restrict__ srcB) {
  for (int i = threadIdx.x; i < GN * 12; i += 256) {
    int n = i / 12, ch = i % 12;
    int g = nb0 + n;
    uint4 v = make_uint4(0, 0, 0, 0);
    if (g < NN) {
      if (ch < 4) {
        float4 f0 = *reinterpret_cast<const float4*>(srcA + (size_t)g * 32 + ch * 8);
        float4 f1 = *reinterpret_cast<const float4*>(srcA + (size_t)g * 32 + ch * 8 + 4);
        v = pack8(f0, f1);
      } else {
        v = *reinterpret_cast<const uint4*>(srcB + (size_t)g * 64 + (ch - 4) * 8);
      }
    }
    *reinterpret_cast<uint4*>(&sA[n * LSTR + ch * 8]) = v;
  }
}

__device__ __forceinline__ void stage_bfbf(unsigned short* sA, int nb0,
                                           const unsigned short* __restrict__ srcA,
                                           const unsigned short* __restrict__ srcB) {
  for (int i = threadIdx.x; i < GN * 12; i += 256) {
    int n = i / 12, ch = i % 12;
    int g = nb0 + n;
    uint4 v = make_uint4(0, 0, 0, 0);
    if (g < NN) {
      if (ch < 4) v = *reinterpret_cast<const uint4*>(srcA + (size_t)g * 96 + ch * 8);
      else v = *reinterpret_cast<const uint4*>(srcB + (size_t)g * 64 + (ch - 4) * 8);
    }
    *reinterpret_cast<uint4*>(&sA[n * LSTR + ch * 8]) = v;
  }
}

template <int NCOLS>
__device__ __forceinline__ void stage_w(unsigned short* sW,
                                        const unsigned short* __restrict__ wt, int t) {
  for (int i = threadIdx.x; i < NCOLS * 12; i += 256) {
    int col = i / 12, ch = i % 12;
    uint4 v = *reinterpret_cast<const uint4*>(wt + col * WSTR + t * 96 + ch * 8);
    *reinterpret_cast<uint4*>(&sW[col * LSTR + ch * 8]) = v;
  }
}

// ---------------- gates: bf16 MFMA GEMM ----------------
__global__ __launch_bounds__(256) void k_rz(const float* __restrict__ x,
                                            const float* __restrict__ h,
                                            const unsigned short* __restrict__ xh1,
                                            const unsigned short* __restrict__ xh2,
                                            const unsigned short* __restrict__ wt_rz,
                                            const float* __restrict__ br,
                                            const float* __restrict__ bz,
                                            unsigned short* __restrict__ rh,
                                            float* __restrict__ zb) {
  __shared__ alignas(16) unsigned short sA[GN * LSTR];
  __shared__ alignas(16) unsigned short sW[128 * LSTR];
  int tid = threadIdx.x;
  int nb0 = blockIdx.x * GN;
  int wv = tid >> 6, l = tid & 63;
  int l15 = l & 15, lg = l >> 4;
  int n0 = wv * 32;

  f32x4 acc[4][2];
#pragma unroll
  for (int nt = 0; nt < 2; ++nt) {
    int colc = n0 + nt * 16 + l15;
    float bias = (colc < 64) ? br[colc] : bz[colc - 64];
#pragma unroll
    for (int mt = 0; mt < 4; ++mt) acc[mt][nt] = {bias, bias, bias, bias};
  }

#pragma unroll
  for (int t = 0; t < 3; ++t) {
    if (t == 0) stage_f32f32(sA, nb0, x, h);
    else if (t == 1) stage_copy96(sA, nb0, xh1);
    else stage_copy96(sA, nb0, xh2);
    stage_w<128>(sW, wt_rz, t);
    __syncthreads();
#pragma unroll
    for (int ks = 0; ks < 3; ++ks) {
      int kb = ks * 32 + lg * 8;
      s16x8 af[4];
#pragma unroll
      for (int mt = 0; mt < 4; ++mt)
        af[mt] = *reinterpret_cast<const s16x8*>(&sA[(mt * 16 + l15) * LSTR + kb]);
      s16x8 bf0 = *reinterpret_cast<const s16x8*>(&sW[(n0 + l15) * LSTR + kb]);
      s16x8 bf1 = *reinterpret_cast<const s16x8*>(&sW[(n0 + 16 + l15) * LSTR + kb]);
#pragma unroll
      for (int mt = 0; mt < 4; ++mt) {
        acc[mt][0] = __builtin_amdgcn_mfma_f32_16x16x32_bf16(af[mt], bf0, acc[mt][0], 0, 0, 0);
        acc[mt][1] = __builtin_amdgcn_mfma_f32_16x16x32_bf16(af[mt], bf1, acc[mt][1], 0, 0, 0);
      }
    }
    __syncthreads();
  }

#pragma unroll
  for (int mt = 0; mt < 4; ++mt) {
#pragma unroll
    for (int nt = 0; nt < 2; ++nt) {
      int colc = n0 + nt * 16 + l15;
#pragma unroll
      for (int r = 0; r < 4; ++r) {
        int g = nb0 + mt * 16 + lg * 4 + r;
        if (g < NN) {
          float pre = acc[mt][nt][r];
          float sg = 1.f / (1.f + expf(-pre));
          if (colc < 64) {
            float hv = h[(size_t)g * 64 + colc];
            rh[(size_t)g * 64 + colc] = (unsigned short)bfbits(sg * hv);
          } else {
            zb[(size_t)g * 64 + (colc - 64)] = sg;
          }
        }
      }
    }
  }
}

__global__ __launch_bounds__(256) void k_c(const float* __restrict__ x,
                                           const float* __restrict__ h,
                                           const unsigned short* __restrict__ rhf,
                                           const unsigned short* __restrict__ xh1,
                                           const unsigned short* __restrict__ xh2,
                                           const unsigned short* __restrict__ rh1,
                                           const unsigned short* __restrict__ rh2,
                                           const unsigned short* __restrict__ wt_c,
                                           const float* __restrict__ bc,
                                           const float* __restrict__ zb,
                                           float* __restrict__ out) {
  __shared__ alignas(16) unsigned short sA[GN * LSTR];
  __shared__ alignas(16) unsigned short sW[64 * LSTR];
  int tid = threadIdx.x;
  int nb0 = blockIdx.x * GN;
  int wv = tid >> 6, l = tid & 63;
  int l15 = l & 15, lg = l >> 4;
  int n0 = wv * 16;

  float bias = bc[n0 + l15];
  f32x4 acc[4];
#pragma unroll
  for (int mt = 0; mt < 4; ++mt) acc[mt] = {bias, bias, bias, bias};

#pragma unroll
  for (int t = 0; t < 3; ++t) {
    if (t == 0) stage_f32bf(sA, nb0, x, rhf);
    else if (t == 1) stage_bfbf(sA, nb0, xh1, rh1);
    else stage_bfbf(sA, nb0, xh2, rh2);
    stage_w<64>(sW, wt_c, t);
    __syncthreads();
#pragma unroll
    for (int ks = 0; ks < 3; ++ks) {
      int kb = ks * 32 + lg * 8;
      s16x8 bf0 = *reinterpret_cast<const s16x8*>(&sW[(n0 + l15) * LSTR + kb]);
#pragma unroll
      for (int mt = 0; mt < 4; ++mt) {
        s16x8 af = *reinterpret_cast<const s16x8*>(&sA[(mt * 16 + l15) * LSTR + kb]);
        acc[mt] = __builtin_amdgcn_mfma_f32_16x16x32_bf16(af, bf0, acc[mt], 0, 0, 0);
      }
    }
    __syncthreads();
  }

  int colc = n0 + l15;
#pragma unroll
  for (int mt = 0; mt < 4; ++mt) {
#pragma unroll
    for (int r = 0; r < 4; ++r) {
      int g = nb0 + mt * 16 + lg * 4 + r;
      if (g < NN) {
        float cv = tanhf(acc[mt][r]);
        float z = zb[(size_t)g * 64 + colc];
        float hv = h[(size_t)g * 64 + colc];
        out[(size_t)g * 64 + colc] = z * hv + (1.f - z) * cv;
      }
    }
  }
}

// ---------------- launch ----------------
extern "C" void kernel_launch(void* const* d_in, const int* in_sizes, int n_in,
                              void* d_out, int out_size, void* d_ws, size_t ws_size,
                              hipStream_t stream) {
  const float* x = (const float*)d_in[0];
  const float* h = (const float*)d_in[1];
  const int* eidx = (const int*)d_in[2];
  const float* ew = (const float*)d_in[3];
  const float* Wr = (const float*)d_in[4];
  const float* br = (const float*)d_in[5];
  const float* Wz = (const float*)d_in[6];
  const float* bz = (const float*)d_in[7];
  const float* Wc = (const float*)d_in[8];
  const float* bc = (const float*)d_in[9];
  const int* src = eidx;
  const int* dst = eidx + NE;
  float* out = (float*)d_out;

  int* ip = (int*)d_ws;
  int* gcur1 = ip;                          // 512
  int* gcur2 = ip + 512;                    // 512
  int* deg_out = ip + 1024;                 // NN
  int* cursor = deg_out + NN;               // NN
  int2* rec1 = (int2*)(cursor + NN);        // NBINS*BCAP int2
  unsigned char* rec2 = (unsigned char*)(rec1 + (size_t)NBINS * BCAP);  // NBINS*BCAP
  int2* ell = (int2*)(rec2 + ((size_t)NBINS * BCAP + 8) / 8 * 8);       // NN*ECAP
  float* zb = (float*)(ell + (size_t)NN * ECAP);                        // NN*64 f32
  unsigned short* xh0 = (unsigned short*)(zb + (size_t)NN * 64);        // NN*96 bf16
  unsigned short* xh1 = xh0 + (size_t)NN * 96;
  unsigned short* xh2 = xh1 + (size_t)NN * 96;
  unsigned short* rh  = xh2 + (size_t)NN * 96;   // NN*64 bf16
  unsigned short* rh1 = rh + (size_t)NN * 64;
  unsigned short* rh2 = rh1 + (size_t)NN * 64;
  unsigned short* wt_rz = rh2 + (size_t)NN * 64; // 128*WSTR
  unsigned short* wt_c = wt_rz + 128 * WSTR;     // 64*WSTR

  hipMemsetAsync(ip, 0, 1024 * sizeof(int), stream);

  dim3 blk(256);
  k_wprep<<<dim3((192 * 36 + 255) / 256), blk, 0, stream>>>(Wr, Wz, Wc, wt_rz, wt_c);
  k_binA<<<dim3(NBLKA), blk, 0, stream>>>(src, dst, ew, gcur1, gcur2, rec1, rec2);
  k_bdeg<<<dim3(NBINS), blk, 0, stream>>>(gcur2, rec2, deg_out);
  k_bell<<<dim3(NBINS), blk, 0, stream>>>(gcur1, rec1, deg_out, ell, cursor);
  k_xh0<<<dim3(NN * 48 / 256), blk, 0, stream>>>(x, h, (unsigned int*)xh0);

  k_prop96e<<<dim3(NN / 8), blk, 0, stream>>>((const uint2*)xh0, (uint2*)xh1,
                                              cursor, ell);
  k_prop96e<<<dim3(NN / 8), blk, 0, stream>>>((const uint2*)xh1, (uint2*)xh2,
                                              cursor, ell);
  k_rz<<<dim3((NN + GN - 1) / GN), blk, 0, stream>>>(x, h, xh1, xh2, wt_rz, br, bz, rh, zb);
  k_prop64e<<<dim3(NN / 8), blk, 0, stream>>>((const unsigned int*)rh,
                                              (unsigned int*)rh1, cursor, ell);
  k_prop64e<<<dim3(NN / 8), blk, 0, stream>>>((const unsigned int*)rh1,
                                              (unsigned int*)rh2, cursor, ell);
  k_c<<<dim3((NN + GN - 1) / GN), blk, 0, stream>>>(x, h, rh, xh1, xh2, rh1, rh2,
                                                    wt_c, bc, zb, out);
}

// Round 11
// 387.501 us; speedup vs baseline: 1.1300x; 1.1012x over previous
//
#include <hip/hip_runtime.h>
#include <math.h>

#define NN 100000
#define NE 1600000
#define ECAP 64      // ELL slots/node
#define GN 64        // nodes per gate-GEMM block
#define WSTR 296     // W^T row stride in ushorts
#define LSTR 104     // LDS bf16 row stride (96 + 8)

// binned build
#define EPB 4096     // edges per phase-A block
#define NBLKA 391    // ceil(NE/EPB)
#define BINB 256     // nodes per bin
#define NBINS 391    // ceil(NN/BINB)
#define BCAP 4736    // records per bin (mean 4092, +10 sigma)

typedef __attribute__((ext_vector_type(4))) float f32x4;
typedef __attribute__((ext_vector_type(8))) short s16x8;

__device__ __forceinline__ unsigned int bfbits(float v) {
  unsigned int b = __float_as_uint(v);
  b += 0x7fffu + ((b >> 16) & 1u);
  return b >> 16;
}
__device__ __forceinline__ float bflo(unsigned int v) { return __uint_as_float(v << 16); }
__device__ __forceinline__ float bfhi(unsigned int v) { return __uint_as_float(v & 0xffff0000u); }
__device__ __forceinline__ float bf1(unsigned short v) { return __uint_as_float((unsigned int)v << 16); }

// ---------------- binned graph build ----------------
__global__ __launch_bounds__(256) void k_binA(const int* __restrict__ src,
                                              const int* __restrict__ dst,
                                              const float* __restrict__ ew,
                                              int* __restrict__ gcur1,
                                              int* __restrict__ gcur2,
                                              int2* __restrict__ rec1,
                                              unsigned char* __restrict__ rec2) {
  __shared__ int h1[NBINS], h2[NBINS];
  int tid = threadIdx.x;
  for (int t = tid; t < NBINS; t += 256) { h1[t] = 0; h2[t] = 0; }
  __syncthreads();
  int base = blockIdx.x * EPB;
  int end = base + EPB; if (end > NE) end = NE;
  for (int e = base + tid; e < end; e += 256) {
    atomicAdd(&h1[dst[e] >> 8], 1);
    atomicAdd(&h2[src[e] >> 8], 1);
  }
  __syncthreads();
  for (int t = tid; t < NBINS; t += 256) {
    int c1 = h1[t];
    h1[t] = t * BCAP + (c1 ? atomicAdd(&gcur1[t], c1) : 0);
    int c2 = h2[t];
    h2[t] = t * BCAP + (c2 ? atomicAdd(&gcur2[t], c2) : 0);
  }
  __syncthreads();
  for (int e = base + tid; e < end; e += 256) {
    int d = dst[e], s = src[e];
    int p1 = atomicAdd(&h1[d >> 8], 1);
    rec1[p1] = make_int2(s | ((d & 255) << 20), __float_as_int(ew[e]));
    int p2 = atomicAdd(&h2[s >> 8], 1);
    rec2[p2] = (unsigned char)(s & 255);
  }
}

__global__ __launch_bounds__(256) void k_bdeg(const int* __restrict__ gcur2,
                                              const unsigned char* __restrict__ rec2,
                                              int* __restrict__ deg_out) {
  __shared__ int lc[BINB];
  int b = blockIdx.x, tid = threadIdx.x;
  lc[tid] = 0;
  __syncthreads();
  int cnt = gcur2[b];
  const unsigned char* rp = rec2 + (size_t)b * BCAP;
  for (int i = tid; i < cnt; i += 256) atomicAdd(&lc[rp[i]], 1);
  __syncthreads();
  int node = b * 256 + tid;
  if (node < NN) deg_out[node] = lc[tid];
}

// ELL fill with normalization applied here (deg_out ready).
__global__ __launch_bounds__(256) void k_bell(const int* __restrict__ gcur1,
                                              const int2* __restrict__ rec1,
                                              const int* __restrict__ deg_out,
                                              int2* __restrict__ ell,
                                              int* __restrict__ cursor) {
  __shared__ int lc[BINB];
  int b = blockIdx.x, tid = threadIdx.x;
  lc[tid] = 0;
  __syncthreads();
  int cnt = gcur1[b];
  const int2* rp = rec1 + (size_t)b * BCAP;
  for (int i = tid; i < cnt; i += 256) {
    int2 r = rp[i];
    int s = r.x & 0xFFFFF;
    int dl = (r.x >> 20) & 255;
    float w = __int_as_float(r.y) / fmaxf((float)deg_out[s], 1.0f);
    int p = atomicAdd(&lc[dl], 1);
    if (p < ECAP)
      ell[(size_t)(b * 256 + dl) * ECAP + p] = make_int2(s, __float_as_int(w));
  }
  __syncthreads();
  int node = b * 256 + tid;
  if (node < NN) cursor[node] = lc[tid];
}

// ---------------- xh0 = bf16 concat(x,h) ----------------
__global__ __launch_bounds__(256) void k_xh0(const float* __restrict__ x,
                                             const float* __restrict__ h,
                                             unsigned int* __restrict__ xh0) {
  int idx = blockIdx.x * 256 + threadIdx.x;
  if (idx >= NN * 48) return;
  int n = idx / 48, c = idx - n * 48;
  float v0, v1;
  if (c < 16) {
    v0 = x[(size_t)n * 32 + 2 * c];
    v1 = x[(size_t)n * 32 + 2 * c + 1];
  } else {
    v0 = h[(size_t)n * 64 + 2 * (c - 16)];
    v1 = h[(size_t)n * 64 + 2 * (c - 16) + 1];
  }
  xh0[idx] = bfbits(v0) | (bfbits(v1) << 16);
}

// ---------------- W prep ----------------
__global__ __launch_bounds__(256) void k_wprep(const float* __restrict__ Wr,
                                               const float* __restrict__ Wz,
                                               const float* __restrict__ Wc,
                                               unsigned short* __restrict__ wt_rz,
                                               unsigned short* __restrict__ wt_c) {
  int idx = blockIdx.x * 256 + threadIdx.x;
  if (idx >= 192 * 36) return;
  int col = idx % 192;
  int k0 = (idx / 192) * 8;
  unsigned int packed[4];
#pragma unroll
  for (int p = 0; p < 4; ++p) {
    unsigned int lo, hi;
#pragma unroll
    for (int e = 0; e < 2; ++e) {
      int k = k0 + p * 2 + e;
      int t = k / 96, kl = k - t * 96;
      float v;
      if (col < 64) v = Wr[t * 6144 + kl * 64 + col];
      else if (col < 128) v = Wz[t * 6144 + kl * 64 + (col - 64)];
      else v = Wc[t * 6144 + kl * 64 + (col - 128)];
      if (e == 0) lo = bfbits(v); else hi = bfbits(v);
    }
    packed[p] = lo | (hi << 16);
  }
  unsigned short* dstp = (col < 128) ? (wt_rz + col * WSTR + k0)
                                     : (wt_c + (col - 128) * WSTR + k0);
  *reinterpret_cast<uint4*>(dstp) =
      make_uint4(packed[0], packed[1], packed[2], packed[3]);
}

// ---------------- propagation: half-wave per node, ELL, 4x unrolled ----------
__global__ __launch_bounds__(256) void k_prop96e(const uint2* __restrict__ in,
                                                 uint2* __restrict__ out,
                                                 const int* __restrict__ cnt_arr,
                                                 const int2* __restrict__ ell) {
  int hw = (blockIdx.x * 256 + threadIdx.x) >> 5;
  int lane = threadIdx.x & 31;
  if (hw >= NN) return;
  int cnt = cnt_arr[hw];
  if (cnt > ECAP) cnt = ECAP;
  const int2* ep = ell + (size_t)hw * ECAP;
  bool act = lane < 24;
  float a0 = 0.f, a1 = 0.f, a2 = 0.f, a3 = 0.f;
  float b0 = 0.f, b1 = 0.f, b2 = 0.f, b3 = 0.f;
  int i = 0;
  for (; i + 4 <= cnt; i += 4) {
    int2 e0 = ep[i], e1 = ep[i + 1], e2 = ep[i + 2], e3 = ep[i + 3];
    if (act) {
      uint2 v0 = in[(size_t)e0.x * 24 + lane];
      uint2 v1 = in[(size_t)e1.x * 24 + lane];
      uint2 v2 = in[(size_t)e2.x * 24 + lane];
      uint2 v3 = in[(size_t)e3.x * 24 + lane];
      float w0 = __int_as_float(e0.y), w1 = __int_as_float(e1.y);
      float w2 = __int_as_float(e2.y), w3 = __int_as_float(e3.y);
      a0 = fmaf(w0, bflo(v0.x), a0); a1 = fmaf(w0, bfhi(v0.x), a1);
      a2 = fmaf(w0, bflo(v0.y), a2); a3 = fmaf(w0, bfhi(v0.y), a3);
      b0 = fmaf(w1, bflo(v1.x), b0); b1 = fmaf(w1, bfhi(v1.x), b1);
      b2 = fmaf(w1, bflo(v1.y), b2); b3 = fmaf(w1, bfhi(v1.y), b3);
      a0 = fmaf(w2, bflo(v2.x), a0); a1 = fmaf(w2, bfhi(v2.x), a1);
      a2 = fmaf(w2, bflo(v2.y), a2); a3 = fmaf(w2, bfhi(v2.y), a3);
      b0 = fmaf(w3, bflo(v3.x), b0); b1 = fmaf(w3, bfhi(v3.x), b1);
      b2 = fmaf(w3, bflo(v3.y), b2); b3 = fmaf(w3, bfhi(v3.y), b3);
    }
  }
  for (; i < cnt; ++i) {
    int2 e = ep[i];
    if (act) {
      uint2 v = in[(size_t)e.x * 24 + lane];
      float w = __int_as_float(e.y);
      a0 = fmaf(w, bflo(v.x), a0); a1 = fmaf(w, bfhi(v.x), a1);
      a2 = fmaf(w, bflo(v.y), a2); a3 = fmaf(w, bfhi(v.y), a3);
    }
  }
  if (act) {
    uint2 o;
    o.x = bfbits(a0 + b0) | (bfbits(a1 + b1) << 16);
    o.y = bfbits(a2 + b2) | (bfbits(a3 + b3) << 16);
    out[(size_t)hw * 24 + lane] = o;
  }
}

__global__ __launch_bounds__(256) void k_prop64e(const unsigned int* __restrict__ in,
                                                 unsigned int* __restrict__ out,
                                                 const int* __restrict__ cnt_arr,
                                                 const int2* __restrict__ ell) {
  int hw = (blockIdx.x * 256 + threadIdx.x) >> 5;
  int lane = threadIdx.x & 31;
  if (hw >= NN) return;
  int cnt = cnt_arr[hw];
  if (cnt > ECAP) cnt = ECAP;
  const int2* ep = ell + (size_t)hw * ECAP;
  float a0 = 0.f, a1 = 0.f, b0 = 0.f, b1 = 0.f;
  int i = 0;
  for (; i + 4 <= cnt; i += 4) {
    int2 e0 = ep[i], e1 = ep[i + 1], e2 = ep[i + 2], e3 = ep[i + 3];
    unsigned int v0 = in[(size_t)e0.x * 32 + lane];
    unsigned int v1 = in[(size_t)e1.x * 32 + lane];
    unsigned int v2 = in[(size_t)e2.x * 32 + lane];
    unsigned int v3 = in[(size_t)e3.x * 32 + lane];
    float w0 = __int_as_float(e0.y), w1 = __int_as_float(e1.y);
    float w2 = __int_as_float(e2.y), w3 = __int_as_float(e3.y);
    a0 = fmaf(w0, bflo(v0), a0); a1 = fmaf(w0, bfhi(v0), a1);
    b0 = fmaf(w1, bflo(v1), b0); b1 = fmaf(w1, bfhi(v1), b1);
    a0 = fmaf(w2, bflo(v2), a0); a1 = fmaf(w2, bfhi(v2), a1);
    b0 = fmaf(w3, bflo(v3), b0); b1 = fmaf(w3, bfhi(v3), b1);
  }
  for (; i < cnt; ++i) {
    int2 e = ep[i];
    unsigned int v = in[(size_t)e.x * 32 + lane];
    float w = __int_as_float(e.y);
    a0 = fmaf(w, bflo(v), a0); a1 = fmaf(w, bfhi(v), a1);
  }
  out[(size_t)hw * 32 + lane] = bfbits(a0 + b0) | (bfbits(a1 + b1) << 16);
}

// ---------------- gate staging (plain bf16 copies) ----------------
// full 96 cols from bf16 src (ld 96)
__device__ __forceinline__ void stage_copy96(unsigned short* sA, int nb0,
                                             const unsigned short* __restrict__ src) {
  for (int i = threadIdx.x; i < GN * 12; i += 256) {
    int n = i / 12, ch = i % 12;
    int g = nb0 + n;
    uint4 v = make_uint4(0, 0, 0, 0);
    if (g < NN) v = *reinterpret_cast<const uint4*>(src + (size_t)g * 96 + ch * 8);
    *reinterpret_cast<uint4*>(&sA[n * LSTR + ch * 8]) = v;
  }
}

// first 32 cols from bf16 96-wide srcA, last 64 cols from bf16 64-wide srcB
__device__ __forceinline__ void stage_bfbf(unsigned short* sA, int nb0,
                                           const unsigned short* __restrict__ srcA,
                                           const unsigned short* __restrict__ srcB) {
  for (int i = threadIdx.x; i < GN * 12; i += 256) {
    int n = i / 12, ch = i % 12;
    int g = nb0 + n;
    uint4 v = make_uint4(0, 0, 0, 0);
    if (g < NN) {
      if (ch < 4) v = *reinterpret_cast<const uint4*>(srcA + (size_t)g * 96 + ch * 8);
      else v = *reinterpret_cast<const uint4*>(srcB + (size_t)g * 64 + (ch - 4) * 8);
    }
    *reinterpret_cast<uint4*>(&sA[n * LSTR + ch * 8]) = v;
  }
}

// ---------------- gates: bf16 MFMA GEMM, W from global (L2) ----------------
__global__ __launch_bounds__(256) void k_rz(const unsigned short* __restrict__ xh0,
                                            const unsigned short* __restrict__ xh1,
                                            const unsigned short* __restrict__ xh2,
                                            const unsigned short* __restrict__ wt_rz,
                                            const float* __restrict__ br,
                                            const float* __restrict__ bz,
                                            unsigned short* __restrict__ rh,
                                            unsigned short* __restrict__ zbb) {
  __shared__ alignas(16) unsigned short sA[GN * LSTR];
  int tid = threadIdx.x;
  int nb0 = blockIdx.x * GN;
  int wv = tid >> 6, l = tid & 63;
  int l15 = l & 15, lg = l >> 4;
  int n0 = wv * 32;

  f32x4 acc[4][2];
#pragma unroll
  for (int nt = 0; nt < 2; ++nt) {
    int colc = n0 + nt * 16 + l15;
    float bias = (colc < 64) ? br[colc] : bz[colc - 64];
#pragma unroll
    for (int mt = 0; mt < 4; ++mt) acc[mt][nt] = {bias, bias, bias, bias};
  }

  // per-wave W base pointers (L2-resident; 16 rows x 64B contiguous per read)
  const unsigned short* w0p = wt_rz + (size_t)(n0 + l15) * WSTR + lg * 8;
  const unsigned short* w1p = wt_rz + (size_t)(n0 + 16 + l15) * WSTR + lg * 8;

#pragma unroll
  for (int t = 0; t < 3; ++t) {
    if (t == 0) stage_copy96(sA, nb0, xh0);
    else if (t == 1) stage_copy96(sA, nb0, xh1);
    else stage_copy96(sA, nb0, xh2);
    __syncthreads();
#pragma unroll
    for (int ks = 0; ks < 3; ++ks) {
      int kb = ks * 32 + lg * 8;
      s16x8 bf0 = *reinterpret_cast<const s16x8*>(w0p + t * 96 + ks * 32);
      s16x8 bf1 = *reinterpret_cast<const s16x8*>(w1p + t * 96 + ks * 32);
#pragma unroll
      for (int mt = 0; mt < 4; ++mt) {
        s16x8 af = *reinterpret_cast<const s16x8*>(&sA[(mt * 16 + l15) * LSTR + kb]);
        acc[mt][0] = __builtin_amdgcn_mfma_f32_16x16x32_bf16(af, bf0, acc[mt][0], 0, 0, 0);
        acc[mt][1] = __builtin_amdgcn_mfma_f32_16x16x32_bf16(af, bf1, acc[mt][1], 0, 0, 0);
      }
    }
    __syncthreads();
  }

#pragma unroll
  for (int mt = 0; mt < 4; ++mt) {
#pragma unroll
    for (int nt = 0; nt < 2; ++nt) {
      int colc = n0 + nt * 16 + l15;
#pragma unroll
      for (int r = 0; r < 4; ++r) {
        int g = nb0 + mt * 16 + lg * 4 + r;
        if (g < NN) {
          float pre = acc[mt][nt][r];
          float sg = 1.f / (1.f + expf(-pre));
          if (colc < 64) {
            float hv = bf1(xh0[(size_t)g * 96 + 32 + colc]);
            rh[(size_t)g * 64 + colc] = (unsigned short)bfbits(sg * hv);
          } else {
            zbb[(size_t)g * 64 + (colc - 64)] = (unsigned short)bfbits(sg);
          }
        }
      }
    }
  }
}

__global__ __launch_bounds__(256) void k_c(const unsigned short* __restrict__ xh0,
                                           const unsigned short* __restrict__ rhf,
                                           const unsigned short* __restrict__ xh1,
                                           const unsigned short* __restrict__ xh2,
                                           const unsigned short* __restrict__ rh1,
                                           const unsigned short* __restrict__ rh2,
                                           const unsigned short* __restrict__ wt_c,
                                           const float* __restrict__ bc,
                                           const unsigned short* __restrict__ zbb,
                                           float* __restrict__ out) {
  __shared__ alignas(16) unsigned short sA[GN * LSTR];
  int tid = threadIdx.x;
  int nb0 = blockIdx.x * GN;
  int wv = tid >> 6, l = tid & 63;
  int l15 = l & 15, lg = l >> 4;
  int n0 = wv * 16;

  float bias = bc[n0 + l15];
  f32x4 acc[4];
#pragma unroll
  for (int mt = 0; mt < 4; ++mt) acc[mt] = {bias, bias, bias, bias};

  const unsigned short* wp = wt_c + (size_t)(n0 + l15) * WSTR + lg * 8;

#pragma unroll
  for (int t = 0; t < 3; ++t) {
    if (t == 0) stage_bfbf(sA, nb0, xh0, rhf);
    else if (t == 1) stage_bfbf(sA, nb0, xh1, rh1);
    else stage_bfbf(sA, nb0, xh2, rh2);
    __syncthreads();
#pragma unroll
    for (int ks = 0; ks < 3; ++ks) {
      int kb = ks * 32 + lg * 8;
      s16x8 bf0 = *reinterpret_cast<const s16x8*>(wp + t * 96 + ks * 32);
#pragma unroll
      for (int mt = 0; mt < 4; ++mt) {
        s16x8 af = *reinterpret_cast<const s16x8*>(&sA[(mt * 16 + l15) * LSTR + kb]);
        acc[mt] = __builtin_amdgcn_mfma_f32_16x16x32_bf16(af, bf0, acc[mt], 0, 0, 0);
      }
    }
    __syncthreads();
  }

  int colc = n0 + l15;
#pragma unroll
  for (int mt = 0; mt < 4; ++mt) {
#pragma unroll
    for (int r = 0; r < 4; ++r) {
      int g = nb0 + mt * 16 + lg * 4 + r;
      if (g < NN) {
        float cv = tanhf(acc[mt][r]);
        float z = bf1(zbb[(size_t)g * 64 + colc]);
        float hv = bf1(xh0[(size_t)g * 96 + 32 + colc]);
        out[(size_t)g * 64 + colc] = z * hv + (1.f - z) * cv;
      }
    }
  }
}

// ---------------- launch ----------------
extern "C" void kernel_launch(void* const* d_in, const int* in_sizes, int n_in,
                              void* d_out, int out_size, void* d_ws, size_t ws_size,
                              hipStream_t stream) {
  const float* x = (const float*)d_in[0];
  const float* h = (const float*)d_in[1];
  const int* eidx = (const int*)d_in[2];
  const float* ew = (const float*)d_in[3];
  const float* Wr = (const float*)d_in[4];
  const float* br = (const float*)d_in[5];
  const float* Wz = (const float*)d_in[6];
  const float* bz = (const float*)d_in[7];
  const float* Wc = (const float*)d_in[8];
  const float* bc = (const float*)d_in[9];
  const int* src = eidx;
  const int* dst = eidx + NE;
  float* out = (float*)d_out;

  int* ip = (int*)d_ws;
  int* gcur1 = ip;                          // 512
  int* gcur2 = ip + 512;                    // 512
  int* deg_out = ip + 1024;                 // NN
  int* cursor = deg_out + NN;               // NN
  int2* rec1 = (int2*)(cursor + NN);        // NBINS*BCAP int2
  unsigned char* rec2 = (unsigned char*)(rec1 + (size_t)NBINS * BCAP);  // NBINS*BCAP
  int2* ell = (int2*)(rec2 + ((size_t)NBINS * BCAP + 8) / 8 * 8);       // NN*ECAP
  unsigned short* zbb = (unsigned short*)(ell + (size_t)NN * ECAP);     // NN*64 bf16
  unsigned short* xh0 = zbb + (size_t)NN * 64;                          // NN*96 bf16
  unsigned short* xh1 = xh0 + (size_t)NN * 96;
  unsigned short* xh2 = xh1 + (size_t)NN * 96;
  unsigned short* rh  = xh2 + (size_t)NN * 96;   // NN*64 bf16
  unsigned short* rh1 = rh + (size_t)NN * 64;
  unsigned short* rh2 = rh1 + (size_t)NN * 64;
  unsigned short* wt_rz = rh2 + (size_t)NN * 64; // 128*WSTR
  unsigned short* wt_c = wt_rz + 128 * WSTR;     // 64*WSTR

  hipMemsetAsync(ip, 0, 1024 * sizeof(int), stream);

  dim3 blk(256);
  k_wprep<<<dim3((192 * 36 + 255) / 256), blk, 0, stream>>>(Wr, Wz, Wc, wt_rz, wt_c);
  k_binA<<<dim3(NBLKA), blk, 0, stream>>>(src, dst, ew, gcur1, gcur2, rec1, rec2);
  k_bdeg<<<dim3(NBINS), blk, 0, stream>>>(gcur2, rec2, deg_out);
  k_bell<<<dim3(NBINS), blk, 0, stream>>>(gcur1, rec1, deg_out, ell, cursor);
  k_xh0<<<dim3(NN * 48 / 256), blk, 0, stream>>>(x, h, (unsigned int*)xh0);

  k_prop96e<<<dim3(NN / 8), blk, 0, stream>>>((const uint2*)xh0, (uint2*)xh1,
                                              cursor, ell);
  k_prop96e<<<dim3(NN / 8), blk, 0, stream>>>((const uint2*)xh1, (uint2*)xh2,
                                              cursor, ell);
  k_rz<<<dim3((NN + GN - 1) / GN), blk, 0, stream>>>(xh0, xh1, xh2, wt_rz, br, bz, rh, zbb);
  k_prop64e<<<dim3(NN / 8), blk, 0, stream>>>((const unsigned int*)rh,
                                              (unsigned int*)rh1, cursor, ell);
  k_prop64e<<<dim3(NN / 8), blk, 0, stream>>>((const unsigned int*)rh1,
                                              (unsigned int*)rh2, cursor, ell);
  k_c<<<dim3((NN + GN - 1) / GN), blk, 0, stream>>>(xh0, rh, xh1, xh2, rh1, rh2,
                                                    wt_c, bc, zbb, out);
}